// Round 2
// baseline (134.182 us; speedup 1.0000x reference)
//
#include <hip/hip_runtime.h>

// SmoothL1 + IoU-matching loss (levels [6400,1600,400], B=8, T=64, 9 groups).
// pred_i layout: (B, 36, L), element (b, a*4+c, l). target: (B, 64, 4).
//
// Semantics kept bit-faithful to the JAX reference:
//  - IEEE f32 divide for IoU (no rcp approximation, no cross-mult compare)
//  - denominator association: ((area_p + area_t) - inter) + eps
//  - strict '>' running max == jnp.argmax first-occurrence tie-break
//  - smooth_l1 with beta=1: ad<1 ? 0.5*ad*ad : ad-0.5

#define NT   64
#define BLK  256
#define L0   6400
#define L1   1600
#define L2   400
#define CH0  25                    // 6400/256
#define CH1  7                     // ceil(1600/256)
#define CH2  2                     // ceil(400/256)
#define CHT  (CH0 + CH1 + CH2)     // 34 chunks per (b,a)

__global__ __launch_bounds__(BLK) void anchor_loss_kernel(
    const float* __restrict__ pred0,
    const float* __restrict__ pred1,
    const float* __restrict__ pred2,
    const float* __restrict__ target,   // B*64*4 floats
    float* __restrict__ g_loss,
    int*   __restrict__ g_cnt)
{
    const int bid   = blockIdx.x;
    const int chunk = bid % CHT;
    const int ba    = bid / CHT;
    const int a     = ba % 9;
    const int b     = ba / 9;

    const float* pred; int L; int lbase;
    if (chunk < CH0)            { pred = pred0; L = L0; lbase = chunk * BLK; }
    else if (chunk < CH0 + CH1) { pred = pred1; L = L1; lbase = (chunk - CH0) * BLK; }
    else                        { pred = pred2; L = L2; lbase = (chunk - CH0 - CH1) * BLK; }

    // Stage this batch's 64 targets: float4 box + precomputed area.
    // Inner-loop reads are wave-uniform -> LDS broadcast, no bank conflicts.
    __shared__ float4 tbox[NT];
    __shared__ float  tarea[NT];
    const int tid = threadIdx.x;
    if (tid < NT)   // 64 threads x float4 = coalesced 1 KiB
        tbox[tid] = ((const float4*)(target + (size_t)b * NT * 4))[tid];
    __syncthreads();
    if (tid < NT) {
        const float4 t4 = tbox[tid];
        tarea[tid] = (t4.z - t4.x) * (t4.w - t4.y);
    }
    __syncthreads();

    const int  l     = lbase + tid;
    const bool valid = (l < L);
    float p0 = 0.f, p1 = 0.f, p2 = 0.f, p3 = 0.f;
    if (valid) {
        const size_t base = ((size_t)b * 36 + (size_t)a * 4) * (size_t)L + (size_t)l;
        p0 = pred[base];
        p1 = pred[base + (size_t)L];
        p2 = pred[base + 2 * (size_t)L];
        p3 = pred[base + 3 * (size_t)L];
    }
    const float area_p = (p2 - p0) * (p3 - p1);

    float best = -1.0f;   // any real iou (incl. negatives) beats this
    int   bi   = 0;
    #pragma unroll 8
    for (int t = 0; t < NT; ++t) {
        const float4 tb = tbox[t];          // ds_read_b128 broadcast
        const float  at = tarea[t];         // ds_read_b32  broadcast
        const float x1 = fmaxf(p0, tb.x);
        const float y1 = fmaxf(p1, tb.y);
        const float x2 = fminf(p2, tb.z);
        const float y2 = fminf(p3, tb.w);
        const float iw = fmaxf(x2 - x1, 0.0f);
        const float ih = fmaxf(y2 - y1, 0.0f);
        const float inter = iw * ih;
        // ((area_p + area_t) - inter) + eps  -- reference association
        const float denom = area_p + at - inter + 1e-6f;
        const float iou   = inter / denom;  // IEEE f32 divide
        if (iou > best) { best = iou; bi = t; }
    }

    float lloss = 0.0f;
    int   lpos  = 0;
    if (valid && best > 0.5f) {
        const float4 tb = tbox[bi];
        float s = 0.0f;
        { float d = p0 - tb.x, ad = fabsf(d); s += (ad < 1.0f) ? 0.5f * ad * ad : ad - 0.5f; }
        { float d = p1 - tb.y, ad = fabsf(d); s += (ad < 1.0f) ? 0.5f * ad * ad : ad - 0.5f; }
        { float d = p2 - tb.z, ad = fabsf(d); s += (ad < 1.0f) ? 0.5f * ad * ad : ad - 0.5f; }
        { float d = p3 - tb.w, ad = fabsf(d); s += (ad < 1.0f) ? 0.5f * ad * ad : ad - 0.5f; }
        lloss = s;
        lpos  = 1;
    }

    // wave(64) shuffle reduce, then cross-wave via LDS, one atomic per block
    #pragma unroll
    for (int off = 32; off > 0; off >>= 1) {
        lloss += __shfl_down(lloss, off);
        lpos  += __shfl_down(lpos,  off);
    }
    __shared__ float wl[BLK / 64];
    __shared__ int   wc[BLK / 64];
    const int wave = tid >> 6;
    if ((tid & 63) == 0) { wl[wave] = lloss; wc[wave] = lpos; }
    __syncthreads();
    if (tid == 0) {
        float s = 0.0f; int c = 0;
        #pragma unroll
        for (int w = 0; w < BLK / 64; ++w) { s += wl[w]; c += wc[w]; }
        atomicAdd(g_loss, s);
        atomicAdd(g_cnt, c);
    }
}

__global__ void finalize_kernel(const float* __restrict__ g_loss,
                                const int*   __restrict__ g_cnt,
                                float* __restrict__ out)
{
    const int n = *g_cnt;
    out[0] = (*g_loss) / (float)(n > 0 ? n : 1);
}

extern "C" void kernel_launch(void* const* d_in, const int* in_sizes, int n_in,
                              void* d_out, int out_size, void* d_ws, size_t ws_size,
                              hipStream_t stream)
{
    (void)in_sizes; (void)n_in; (void)out_size; (void)ws_size;
    const float* pred0  = (const float*)d_in[0];
    const float* pred1  = (const float*)d_in[1];
    const float* pred2  = (const float*)d_in[2];
    const float* target = (const float*)d_in[3];

    float* g_loss = (float*)d_ws;
    int*   g_cnt  = (int*)((char*)d_ws + sizeof(float));

    // d_ws is re-poisoned 0xAA before every timed launch -> zero accumulators.
    hipMemsetAsync(d_ws, 0, 2 * sizeof(float), stream);

    const int grid = 8 * 9 * CHT;   // 2448 blocks x 256 thr = 1 anchor/thread
    anchor_loss_kernel<<<grid, BLK, 0, stream>>>(pred0, pred1, pred2, target,
                                                 g_loss, g_cnt);
    finalize_kernel<<<1, 1, 0, stream>>>(g_loss, g_cnt, (float*)d_out);
}

// Round 3
// 105.871 us; speedup vs baseline: 1.2674x; 1.2674x over previous
//
#include <hip/hip_runtime.h>

// SmoothL1 + IoU-matching loss (levels [6400,1600,400], B=8, T=64, 9 groups).
// pred_i layout: (B, 36, L), element (b, a*4+c, l). target: (B, 64, 4).
//
// Bit-faithful semantics:
//  - IEEE f32 divide for IoU (no rcp, no cross-mult compare)
//  - denominator association: ((area_p + area_t) - inter) + eps
//  - strict '>' running max == jnp.argmax first-occurrence tie-break
//  - smooth_l1 beta=1: ad<1 ? 0.5*ad*ad : ad-0.5
//
// Round-3 structure: 4 contiguous anchors per thread (float4 row loads).
// Rationale: amortize the per-target LDS broadcast over 4x VALU work and
// give 4 independent divide/argmax chains for ILP (round-2 showed
// VALUBusy 44% with VGPR=20 -> dependency-stalled).

#define NT   64
#define BLK  256
#define APT  4                       // anchors per thread
#define SPAN (BLK * APT)             // 1024 anchors per block
#define L0   6400
#define L1   1600
#define L2   400
#define CH0  7                       // ceil(6400/1024)
#define CH1  2                       // ceil(1600/1024)
#define CH2  1                       // ceil(400/1024)
#define CHT  (CH0 + CH1 + CH2)       // 10 chunks per (b,a)

__global__ __launch_bounds__(BLK) void anchor_loss_kernel(
    const float* __restrict__ pred0,
    const float* __restrict__ pred1,
    const float* __restrict__ pred2,
    const float* __restrict__ target,   // B*64*4 floats
    float* __restrict__ g_loss,
    int*   __restrict__ g_cnt)
{
    const int bid   = blockIdx.x;
    const int chunk = bid % CHT;
    const int ba    = bid / CHT;
    const int a     = ba % 9;
    const int b     = ba / 9;

    const float* pred; int L; int lbase;
    if (chunk < CH0)            { pred = pred0; L = L0; lbase = chunk * SPAN; }
    else if (chunk < CH0 + CH1) { pred = pred1; L = L1; lbase = (chunk - CH0) * SPAN; }
    else                        { pred = pred2; L = L2; lbase = (chunk - CH0 - CH1) * SPAN; }

    // Stage this batch's 64 targets: float4 box + precomputed area.
    // Inner-loop reads are wave-uniform -> LDS broadcast, conflict-free.
    __shared__ float4 tbox[NT];
    __shared__ float  tarea[NT];
    const int tid = threadIdx.x;
    if (tid < NT)
        tbox[tid] = ((const float4*)(target + (size_t)b * NT * 4))[tid];
    __syncthreads();
    if (tid < NT) {
        const float4 t4 = tbox[tid];
        tarea[tid] = (t4.z - t4.x) * (t4.w - t4.y);
    }
    __syncthreads();

    // 4 contiguous anchors per thread. All L are multiples of 4 and l0 is a
    // multiple of 4, so the 4 anchors are all-valid or all-invalid together.
    const int  l0    = lbase + tid * APT;
    const bool valid = (l0 < L);

    float p0[APT], p1[APT], p2[APT], p3[APT];
    if (valid) {
        const size_t base = ((size_t)b * 36 + (size_t)a * 4) * (size_t)L + (size_t)l0;
        const float4 r0 = *(const float4*)(pred + base);
        const float4 r1 = *(const float4*)(pred + base + (size_t)L);
        const float4 r2 = *(const float4*)(pred + base + 2 * (size_t)L);
        const float4 r3 = *(const float4*)(pred + base + 3 * (size_t)L);
        p0[0] = r0.x; p0[1] = r0.y; p0[2] = r0.z; p0[3] = r0.w;
        p1[0] = r1.x; p1[1] = r1.y; p1[2] = r1.z; p1[3] = r1.w;
        p2[0] = r2.x; p2[1] = r2.y; p2[2] = r2.z; p2[3] = r2.w;
        p3[0] = r3.x; p3[1] = r3.y; p3[2] = r3.z; p3[3] = r3.w;
    } else {
        #pragma unroll
        for (int j = 0; j < APT; ++j) { p0[j] = p1[j] = p2[j] = p3[j] = 0.f; }
    }

    float ap[APT], best[APT];
    int   bi[APT];
    #pragma unroll
    for (int j = 0; j < APT; ++j) {
        ap[j]   = (p2[j] - p0[j]) * (p3[j] - p1[j]);
        best[j] = -1.0f;           // any real iou beats this
        bi[j]   = 0;
    }

    #pragma unroll 2
    for (int t = 0; t < NT; ++t) {
        const float4 tb = tbox[t];          // ds_read_b128 broadcast
        const float  at = tarea[t];         // ds_read_b32  broadcast
        #pragma unroll
        for (int j = 0; j < APT; ++j) {
            const float x1 = fmaxf(p0[j], tb.x);
            const float y1 = fmaxf(p1[j], tb.y);
            const float x2 = fminf(p2[j], tb.z);
            const float y2 = fminf(p3[j], tb.w);
            const float iw = fmaxf(x2 - x1, 0.0f);
            const float ih = fmaxf(y2 - y1, 0.0f);
            const float inter = iw * ih;
            // ((area_p + area_t) - inter) + eps  -- reference association
            const float denom = ap[j] + at - inter + 1e-6f;
            const float iou   = inter / denom;   // IEEE f32 divide
            if (iou > best[j]) { best[j] = iou; bi[j] = t; }
        }
    }

    float lloss = 0.0f;
    int   lpos  = 0;
    if (valid) {
        #pragma unroll
        for (int j = 0; j < APT; ++j) {
            if (best[j] > 0.5f) {
                const float4 tb = tbox[bi[j]];
                float s = 0.0f;
                { float d = p0[j] - tb.x, ad = fabsf(d); s += (ad < 1.0f) ? 0.5f * ad * ad : ad - 0.5f; }
                { float d = p1[j] - tb.y, ad = fabsf(d); s += (ad < 1.0f) ? 0.5f * ad * ad : ad - 0.5f; }
                { float d = p2[j] - tb.z, ad = fabsf(d); s += (ad < 1.0f) ? 0.5f * ad * ad : ad - 0.5f; }
                { float d = p3[j] - tb.w, ad = fabsf(d); s += (ad < 1.0f) ? 0.5f * ad * ad : ad - 0.5f; }
                lloss += s;
                lpos  += 1;
            }
        }
    }

    // wave(64) shuffle reduce, then cross-wave via LDS, one atomic per block
    #pragma unroll
    for (int off = 32; off > 0; off >>= 1) {
        lloss += __shfl_down(lloss, off);
        lpos  += __shfl_down(lpos,  off);
    }
    __shared__ float wl[BLK / 64];
    __shared__ int   wc[BLK / 64];
    const int wave = tid >> 6;
    if ((tid & 63) == 0) { wl[wave] = lloss; wc[wave] = lpos; }
    __syncthreads();
    if (tid == 0) {
        float s = 0.0f; int c = 0;
        #pragma unroll
        for (int w = 0; w < BLK / 64; ++w) { s += wl[w]; c += wc[w]; }
        atomicAdd(g_loss, s);
        atomicAdd(g_cnt, c);
    }
}

__global__ void finalize_kernel(const float* __restrict__ g_loss,
                                const int*   __restrict__ g_cnt,
                                float* __restrict__ out)
{
    const int n = *g_cnt;
    out[0] = (*g_loss) / (float)(n > 0 ? n : 1);
}

extern "C" void kernel_launch(void* const* d_in, const int* in_sizes, int n_in,
                              void* d_out, int out_size, void* d_ws, size_t ws_size,
                              hipStream_t stream)
{
    (void)in_sizes; (void)n_in; (void)out_size; (void)ws_size;
    const float* pred0  = (const float*)d_in[0];
    const float* pred1  = (const float*)d_in[1];
    const float* pred2  = (const float*)d_in[2];
    const float* target = (const float*)d_in[3];

    float* g_loss = (float*)d_ws;
    int*   g_cnt  = (int*)((char*)d_ws + sizeof(float));

    // d_ws is re-poisoned 0xAA before every timed launch -> zero accumulators.
    hipMemsetAsync(d_ws, 0, 2 * sizeof(float), stream);

    const int grid = 8 * 9 * CHT;   // 720 blocks x 256 thr x 4 anchors/thread
    anchor_loss_kernel<<<grid, BLK, 0, stream>>>(pred0, pred1, pred2, target,
                                                 g_loss, g_cnt);
    finalize_kernel<<<1, 1, 0, stream>>>(g_loss, g_cnt, (float*)d_out);
}